// Round 8
// baseline (2367.332 us; speedup 1.0000x reference)
//
#include <hip/hip_runtime.h>
#include <stdint.h>

// ---------- types / helpers ----------
typedef __attribute__((ext_vector_type(8))) short short8;   // 8 bf16 in 4 VGPRs
typedef __attribute__((ext_vector_type(4))) float f32x4;

__device__ __forceinline__ unsigned short f32_to_bf16(float f) {
    unsigned int u = __float_as_uint(f);
    unsigned int r = (u + 0x7FFF + ((u >> 16) & 1)) >> 16;   // RNE
    return (unsigned short)r;
}
__device__ __forceinline__ float bf16_to_f32(unsigned short s) {
    return __uint_as_float(((unsigned int)s) << 16);
}

__device__ __forceinline__ float sigm_fast(float z) {
    return __fdividef(1.f, 1.f + __expf(-z));
}
__device__ __forceinline__ float tanh_fast(float z) {
    float a = fabsf(z);
    float e = __expf(-2.f * a);                 // in (0,1], no overflow
    float r = __fdividef(1.f - e, 1.f + e);
    return copysignf(r, z);
}

// ---------- prep kernels ----------
__global__ void cvt_bf16_kernel(const float* __restrict__ in,
                                unsigned short* __restrict__ out, int n) {
    int i = (blockIdx.x * blockDim.x + threadIdx.x) * 4;
    if (i >= n) return;
    float4 v = *(const float4*)(in + i);
    ushort4 o;
    o.x = f32_to_bf16(v.x);
    o.y = f32_to_bf16(v.y);
    o.z = f32_to_bf16(v.z);
    o.w = f32_to_bf16(v.w);
    *(ushort4*)(out + i) = o;
}

__global__ void bias_add_kernel(const float* __restrict__ bi,
                                const float* __restrict__ bh,
                                float* __restrict__ bias) {
    int i = blockIdx.x * blockDim.x + threadIdx.x;  // 4096
    bias[i] = bi[i] + bh[i];
}

__global__ void fill_kernel(unsigned int* __restrict__ p, unsigned int v, int n) {
    int i = blockIdx.x * blockDim.x + threadIdx.x;
    if (i < n) p[i] = v;
}

// h0 [b][j] fp32 -> slot 0 of hSeq in B-fragment order:
// dword D = ((kq)*32 + b)*4 + i2, holding bf16 h[j = kq*8 + i2*2], h[j+1] for batch b.
__global__ void hG_init_kernel(const float* __restrict__ h0,
                               unsigned int* __restrict__ hG) {
    int D = blockIdx.x * blockDim.x + threadIdx.x;  // 16384
    int i2 = D & 3, b = (D >> 2) & 31, kq = D >> 7;
    int j = kq * 8 + i2 * 2;
    unsigned int lo = f32_to_bf16(h0[b * 1024 + j]);
    unsigned int hi = f32_to_bf16(h0[b * 1024 + j + 1]);
    hG[D] = lo | (hi << 16);
}

// ---------- phase 1: xg[r][g] = bf16( x[r][:]·W_ih[g][:] + bias[g] ), r=b*512+t ----------
#define LDP 40  // padded LDS row pitch (shorts): 2-way conflicts only (free)

__global__ __launch_bounds__(256) void gemm_xproj(
    const unsigned short* __restrict__ A,   // x bf16 [16384][1024]
    const unsigned short* __restrict__ B,   // W_ih bf16 [4096][1024]
    const float* __restrict__ bias,         // [4096]
    unsigned short* __restrict__ C) {       // xg bf16 [16384][4096]
    __shared__ unsigned short As[64][LDP];
    __shared__ unsigned short Bs[64][LDP];
    const int tid  = threadIdx.x;
    const int lane = tid & 63;
    const int wave = tid >> 6;
    const int m0 = blockIdx.y * 64;
    const int n0 = blockIdx.x * 64;
    const int wm = (wave & 1) * 32;
    const int wn = (wave >> 1) * 32;

    f32x4 acc[2][2] = {};

    const int sr = tid >> 2;
    const int sk = (tid & 3) * 8;
    const int fr = lane & 15;
    const int fk = (lane >> 4) * 8;

    for (int k0 = 0; k0 < 1024; k0 += 32) {
        uint4 av = *(const uint4*)&A[(m0 + sr) * 1024 + k0 + sk];
        uint4 bv = *(const uint4*)&B[(n0 + sr) * 1024 + k0 + sk];
        __syncthreads();
        *(uint4*)&As[sr][sk] = av;
        *(uint4*)&Bs[sr][sk] = bv;
        __syncthreads();
        short8 a0 = *(const short8*)&As[wm + fr][fk];
        short8 a1 = *(const short8*)&As[wm + 16 + fr][fk];
        short8 b0 = *(const short8*)&Bs[wn + fr][fk];
        short8 b1 = *(const short8*)&Bs[wn + 16 + fr][fk];
        acc[0][0] = __builtin_amdgcn_mfma_f32_16x16x32_bf16(a0, b0, acc[0][0], 0, 0, 0);
        acc[0][1] = __builtin_amdgcn_mfma_f32_16x16x32_bf16(a0, b1, acc[0][1], 0, 0, 0);
        acc[1][0] = __builtin_amdgcn_mfma_f32_16x16x32_bf16(a1, b0, acc[1][0], 0, 0, 0);
        acc[1][1] = __builtin_amdgcn_mfma_f32_16x16x32_bf16(a1, b1, acc[1][1], 0, 0, 0);
    }

    const int col = lane & 15;
    const int rq  = (lane >> 4) * 4;
    for (int mt = 0; mt < 2; mt++) {
        for (int nt = 0; nt < 2; nt++) {
            int gcol = n0 + wn + nt * 16 + col;
            float bv = bias[gcol];
            for (int r = 0; r < 4; r++) {
                int grow = m0 + wm + mt * 16 + rq + r;
                C[(size_t)grow * 4096 + gcol] = f32_to_bf16(acc[mt][nt][r] + bv);
            }
        }
    }
}

// ---------- phase 2: persistent recurrence, 64 blocks x 512 threads ----------
// Dataflow core (fresh slot per step, raw sc1 LLC ops, drain-to-zero before any
// load-dest reuse — r5's counted-vmcnt pipelining caused memory faults). r8:
//  * PER-WAVE FLAGS decouple "ready?" from "read": producer wave stores one
//    flag dword flags[slot][bid][wave] AFTER its drained h publish (store+drain
//    in one asm, proven reg-lifetime pattern). Causal chain: h acked at LLC ->
//    flag issued -> consumer sees flag -> h read hits LLC. No sentinels.
//  * CHEAP POLL: wave 0 alone polls the 512 flags (8 dwords/lane = 2 KB/block
//    per retry, ~30x less LLC retry traffic than re-reading 64 KB of h), then
//    broadcasts via monotonic LDS `ready`; waves 1-7 spin locally (free).
//    h data load becomes single-shot guaranteed-hit, no check VALU.
//  * xg prefetched ONE STEP AHEAD, issued after the h drain -> HBM latency
//    never sits inside a critical-path vmcnt(0) drain.
//  * ONE barrier/step (parity-double-buffered partial, pad 16->20 floats);
//    h published straight from epilogue regs (shfl_xor pair-pack).
// Rule #18: sched_barrier(0) after every drain feeding register-only consumers.
__global__ __launch_bounds__(512, 1) void lstm_persist(
    const float* __restrict__ Whh,          // [4096][1024] fp32
    const unsigned short* __restrict__ xg,  // bf16 [16384][4096], bias folded
    const float* __restrict__ c0,           // [32][1024] fp32
    unsigned int* __restrict__ hSeq,        // [512][16384] dwords, frag-order h
    unsigned int* __restrict__ flags,       // [512][64][8] dwords
    float* __restrict__ out) {              // [32][1024] fp32
    __shared__ float partial[2][4][4][32][20];   // 80 KB [par][ks][gate][batch][pad20]
    __shared__ unsigned ready;                   // monotonic: slot s ok when ready >= s+1

    const int tid  = threadIdx.x;
    const int bid  = blockIdx.x;
    const int j0   = bid * 16;
    const int lane = tid & 63;
    const int wave = tid >> 6;
    const int ks   = wave >> 1;   // K-split 0..3 (256 k each)
    const int nt   = wave & 1;    // batch half (0-15 / 16-31)
    const int col  = lane & 15;
    const int quad = lane >> 4;

    if (tid == 0) ready = 0u;

    // ---- stage W_hh slice -> A-fragments in VGPRs/AGPRs (once) ----
    // af[mt][u]: lane holds A[row = mt*16 + col][k-octet = (ks*8+u)*4 + quad].
    short8 af[4][8];
#pragma unroll
    for (int mt = 0; mt < 4; ++mt) {
#pragma unroll
        for (int u = 0; u < 8; ++u) {
            const float* wr = Whh + (size_t)(mt * 1024 + j0 + col) * 1024
                              + (ks * 8 + u) * 32 + quad * 8;
            float4 wa = *(const float4*)wr;
            float4 wb = *(const float4*)(wr + 4);
            short8 v;
            v[0] = (short)f32_to_bf16(wa.x); v[1] = (short)f32_to_bf16(wa.y);
            v[2] = (short)f32_to_bf16(wa.z); v[3] = (short)f32_to_bf16(wa.w);
            v[4] = (short)f32_to_bf16(wb.x); v[5] = (short)f32_to_bf16(wb.y);
            v[6] = (short)f32_to_bf16(wb.z); v[7] = (short)f32_to_bf16(wb.w);
            af[mt][u] = v;
        }
        asm volatile("" ::: "memory");  // cap transient staging register pressure
    }

    const int eb = tid >> 4;     // epilogue batch 0..31
    const int ej = tid & 15;     // epilogue unit  0..15
    float cst = c0[eb * 1024 + j0 + ej];

    const int bofs = nt * 16 + col;    // wave's batch index for B-frag / partial
    // publish dword offset within a slot (t-invariant); even-ej lanes store.
    const int poff = ((bid * 2 + (ej >> 3)) * 32 + eb) * 4 + ((ej & 7) >> 1);

    __syncthreads();

    // prologue: xg gate inputs for t=0 (plain loads; compiler-managed waits)
    const unsigned short* px0 = xg + (size_t)(eb * 512) * 4096 + j0 + ej;
    unsigned short xc0 = px0[0];
    unsigned short xc1 = px0[1024];
    unsigned short xc2 = px0[2048];
    unsigned short xc3 = px0[3072];

    for (int t = 0; t < 512; ++t) {
        // ---- readiness gate for slot t ----
        if (wave == 0) {
            const unsigned int* fp = flags + t * 512 + lane * 8;
            uint4 fa, fb;
            for (;;) {
                asm volatile("global_load_dwordx4 %0, %2, off sc1\n\t"
                             "global_load_dwordx4 %1, %2, off offset:16 sc1"
                             : "=&v"(fa), "=&v"(fb) : "v"(fp) : "memory");
                asm volatile("s_waitcnt vmcnt(0)" ::: "memory");
                __builtin_amdgcn_sched_barrier(0);   // rule #18
                unsigned andv = fa.x & fa.y & fa.z & fa.w & fb.x & fb.y & fb.z & fb.w;
                if (__all(andv != 0u)) break;
                __builtin_amdgcn_s_sleep(1);
            }
            if (lane == 0) *(volatile unsigned*)&ready = (unsigned)(t + 1);
        } else {
            while (*(volatile unsigned*)&ready < (unsigned)(t + 1)) {}
        }

        // ---- h B-fragments: single-shot guaranteed-hit loads ----
        const unsigned int* hR = hSeq + ((size_t)t << 14);
        uint4 bv[8];
#pragma unroll
        for (int u = 0; u < 8; ++u) {
            int kc = ks * 8 + u;
            const unsigned int* p = hR + ((kc * 4 + quad) * 32 + bofs) * 4;
            asm volatile("global_load_dwordx4 %0, %1, off sc1"
                         : "=v"(bv[u]) : "v"(p) : "memory");
        }
        asm volatile("s_waitcnt vmcnt(0)" ::: "memory");
        __builtin_amdgcn_sched_barrier(0);   // rule #18

        // xg prefetch for t+1 (issued NOW so HBM latency hides under
        // MFMA+barrier+epilogue; drained by the publish/flag vmcnt(0))
        unsigned short nx0 = 0, nx1 = 0, nx2 = 0, nx3 = 0;
        if (t < 511) {
            const unsigned short* px = xg + (size_t)(eb * 512 + t + 1) * 4096 + j0 + ej;
            nx0 = px[0];
            nx1 = px[1024];
            nx2 = px[2048];
            nx3 = px[3072];
        }

        f32x4 acc[4] = {};
#pragma unroll
        for (int u = 0; u < 8; ++u) {
            union { uint4 u4; short8 s8; } cv;
            cv.u4 = bv[u];
#pragma unroll
            for (int mt = 0; mt < 4; ++mt)
                acc[mt] = __builtin_amdgcn_mfma_f32_16x16x32_bf16(af[mt][u], cv.s8,
                                                                  acc[mt], 0, 0, 0);
        }
        // write partials: C row (quad*4+r) = unit, C col = batch-local
        const int p = t & 1;
#pragma unroll
        for (int mt = 0; mt < 4; ++mt)
            *(f32x4*)&partial[p][ks][mt][bofs][quad * 4] = acc[mt];
        __syncthreads();                          // the ONE barrier per step

        // epilogue: every thread owns one (batch, unit)
        float z[4];
#pragma unroll
        for (int q = 0; q < 4; ++q)
            z[q] = partial[p][0][q][eb][ej] + partial[p][1][q][eb][ej] +
                   partial[p][2][q][eb][ej] + partial[p][3][q][eb][ej];
        z[0] += bf16_to_f32(xc0);
        z[1] += bf16_to_f32(xc1);
        z[2] += bf16_to_f32(xc2);
        z[3] += bf16_to_f32(xc3);
        float ig = sigm_fast(z[0]);
        float fg = sigm_fast(z[1]);
        float gg = tanh_fast(z[2]);
        float og = sigm_fast(z[3]);
        cst = fg * cst + ig * gg;
        float hn = og * tanh_fast(cst);
        if (t == 511) {                           // uniform: final output, no publish
            out[eb * 1024 + j0 + ej] = hn;
            break;
        }

        // publish straight from registers: pair-pack via shfl, even-ej lanes
        // store one dword; vmcnt(0) INSIDE the asm (store-reg lifetime safety).
        float hp = __shfl_xor(hn, 1);
        unsigned lo16 = f32_to_bf16(hn), hi16 = f32_to_bf16(hp);
        unsigned pack = lo16 | (hi16 << 16);
        unsigned int* pw = hSeq + ((size_t)(t + 1) << 14) + poff;
        if ((ej & 1) == 0) {
            asm volatile("global_store_dword %0, %1, off sc1\n\ts_waitcnt vmcnt(0)"
                         :: "v"(pw), "v"(pack) : "memory");
        }
        // per-wave flag: this wave's h stores are drained (wave-wide vmcnt(0)
        // above) -> flag causally follows data at the LLC.
        if (lane == 0) {
            unsigned one = 1u;
            unsigned int* fw = flags + (t + 1) * 512 + bid * 8 + wave;
            asm volatile("global_store_dword %0, %1, off sc1\n\ts_waitcnt vmcnt(0)"
                         :: "v"(fw), "v"(one) : "memory");
        }
        xc0 = nx0; xc1 = nx1; xc2 = nx2; xc3 = nx3;
    }
}

// ---------- launch ----------
extern "C" void kernel_launch(void* const* d_in, const int* in_sizes, int n_in,
                              void* d_out, int out_size, void* d_ws, size_t ws_size,
                              hipStream_t stream) {
    const float* x    = (const float*)d_in[0];  // [32][512][1024]
    const float* h0   = (const float*)d_in[1];  // [32][1024]
    const float* c0   = (const float*)d_in[2];  // [32][1024]
    const float* Wih  = (const float*)d_in[3];  // [4096][1024]
    const float* Whh  = (const float*)d_in[4];  // [4096][1024]
    const float* b_ih = (const float*)d_in[5];  // [4096]
    const float* b_hh = (const float*)d_in[6];  // [4096]
    float* out = (float*)d_out;
    char* ws = (char*)d_ws;

    // workspace layout (within the proven 176,439,296 B):
    //   xg    @ 0          134217728 B (bf16, live through persistent phase)
    //   xA    @ 134217728   33554432 B (bf16 x; DEAD after gemm -> hSeq overlay:
    //                                   512 slots x 65536 B)
    //   wB    @ 167772160    8388608 B (bf16 W_ih; DEAD after gemm -> flags
    //                                   overlay: 512 x 64 x 8 x 4 = 1 MB)
    //   bias  @ 176160768      16384 B
    unsigned short* xg    = (unsigned short*)(ws);
    unsigned short* xA    = (unsigned short*)(ws + 134217728);
    unsigned short* wB    = (unsigned short*)(ws + 167772160);
    float*          bias  = (float*)(ws + 176160768);
    unsigned int*   hSeq  = (unsigned int*)(ws + 134217728);  // overlays xA
    unsigned int*   flags = (unsigned int*)(ws + 167772160);  // overlays wB

    cvt_bf16_kernel<<<16384, 256, 0, stream>>>(x, xA, 16777216);
    cvt_bf16_kernel<<<4096, 256, 0, stream>>>(Wih, wB, 4194304);
    bias_add_kernel<<<16, 256, 0, stream>>>(b_ih, b_hh, bias);

    dim3 g1(64, 256);
    gemm_xproj<<<g1, 256, 0, stream>>>(xA, wB, bias, xg);

    // xA/wB dead from here. flags: slot 0 = ones (h0 ready), slots 1..511 = 0.
    fill_kernel<<<2, 256, 0, stream>>>(flags, 1u, 512);
    fill_kernel<<<1022, 256, 0, stream>>>(flags + 512, 0u, 511 * 512);
    hG_init_kernel<<<64, 256, 0, stream>>>(h0, hSeq);

    lstm_persist<<<64, 512, 0, stream>>>(Whh, xg, c0, hSeq, flags, out);
}

// Round 9
// 1809.545 us; speedup vs baseline: 1.3082x; 1.3082x over previous
//
#include <hip/hip_runtime.h>
#include <stdint.h>

// ---------- types / helpers ----------
typedef __attribute__((ext_vector_type(8))) short short8;   // 8 bf16 in 4 VGPRs
typedef __attribute__((ext_vector_type(4))) float f32x4;

__device__ __forceinline__ unsigned short f32_to_bf16(float f) {
    unsigned int u = __float_as_uint(f);
    unsigned int r = (u + 0x7FFF + ((u >> 16) & 1)) >> 16;   // RNE
    return (unsigned short)r;
}
__device__ __forceinline__ float bf16_to_f32(unsigned short s) {
    return __uint_as_float(((unsigned int)s) << 16);
}

__device__ __forceinline__ float sigm_fast(float z) {
    return __fdividef(1.f, 1.f + __expf(-z));
}
__device__ __forceinline__ float tanh_fast(float z) {
    float a = fabsf(z);
    float e = __expf(-2.f * a);                 // in (0,1], no overflow
    float r = __fdividef(1.f - e, 1.f + e);
    return copysignf(r, z);
}

// ---------- prep kernels ----------
__global__ void cvt_bf16_kernel(const float* __restrict__ in,
                                unsigned short* __restrict__ out, int n) {
    int i = (blockIdx.x * blockDim.x + threadIdx.x) * 4;
    if (i >= n) return;
    float4 v = *(const float4*)(in + i);
    ushort4 o;
    o.x = f32_to_bf16(v.x);
    o.y = f32_to_bf16(v.y);
    o.z = f32_to_bf16(v.z);
    o.w = f32_to_bf16(v.w);
    *(ushort4*)(out + i) = o;
}

__global__ void bias_add_kernel(const float* __restrict__ bi,
                                const float* __restrict__ bh,
                                float* __restrict__ bias) {
    int i = blockIdx.x * blockDim.x + threadIdx.x;  // 4096
    bias[i] = bi[i] + bh[i];
}

__global__ void fill_kernel(unsigned int* __restrict__ p, unsigned int v, int n) {
    int i = blockIdx.x * blockDim.x + threadIdx.x;
    if (i < n) p[i] = v;
}

// h0 [b][j] fp32 -> slot 0 of hSeq in B-fragment order:
// dword D = ((kq)*32 + b)*4 + i2, holding bf16 h[j = kq*8 + i2*2], h[j+1] for batch b.
__global__ void hG_init_kernel(const float* __restrict__ h0,
                               unsigned int* __restrict__ hG) {
    int D = blockIdx.x * blockDim.x + threadIdx.x;  // 16384
    int i2 = D & 3, b = (D >> 2) & 31, kq = D >> 7;
    int j = kq * 8 + i2 * 2;
    unsigned int lo = f32_to_bf16(h0[b * 1024 + j]);
    unsigned int hi = f32_to_bf16(h0[b * 1024 + j + 1]);
    hG[D] = lo | (hi << 16);
}

// ---------- phase 1: xg[r][g] = bf16( x[r][:]·W_ih[g][:] + bias[g] ), r=b*512+t ----------
// m97 structure (guide ladder step 3, 874-912 TF refcheck'd): 128x128 tile,
// BK=32, 4 waves x (64x64 sub-tile, 4x4 acc), LINEAR LDS [128][32] staged via
// global_load_lds width=16 (wave-uniform LDS base + lane*16; source address
// lane-matched: byte (lane/4)*64+(lane%4)*16 == lane*16). Fragment mapping and
// C/D layout identical to the session's previously-verified 64-tile kernel.
__global__ __launch_bounds__(256) void gemm_xproj(
    const unsigned short* __restrict__ A,   // x bf16 [16384][1024]
    const unsigned short* __restrict__ B,   // W_ih bf16 [4096][1024]
    const float* __restrict__ bias,         // [4096]
    unsigned short* __restrict__ C) {       // xg bf16 [16384][4096]
    __shared__ unsigned short As[128][32];  // 8 KB, linear (global_load_lds: no pad)
    __shared__ unsigned short Bs[128][32];  // 8 KB
    const int tid  = threadIdx.x;
    const int lane = tid & 63;
    const int wave = tid >> 6;
    const int m0 = blockIdx.y * 128;
    const int n0 = blockIdx.x * 128;
    const int wm = (wave & 1) * 64;
    const int wn = (wave >> 1) * 64;

    f32x4 acc[4][4] = {};   // [mt][nt]

    // staging addresses: instruction i covers rows [i*64 + wave*16, +16)
    const int srow = wave * 16 + (lane >> 2);
    const int scol = (lane & 3) * 8;
    const unsigned short* gA0 = A + (size_t)(m0 + srow) * 1024 + scol;
    const unsigned short* gA1 = A + (size_t)(m0 + srow + 64) * 1024 + scol;
    const unsigned short* gB0 = B + (size_t)(n0 + srow) * 1024 + scol;
    const unsigned short* gB1 = B + (size_t)(n0 + srow + 64) * 1024 + scol;
    unsigned short* lA0 = &As[wave * 16][0];        // wave-uniform bases
    unsigned short* lA1 = &As[64 + wave * 16][0];
    unsigned short* lB0 = &Bs[wave * 16][0];
    unsigned short* lB1 = &Bs[64 + wave * 16][0];

    const int fr = lane & 15;
    const int fo = (lane >> 4) * 8;

    for (int k0 = 0; k0 < 1024; k0 += 32) {
        __syncthreads();                    // prev-iter fragment reads done
        __builtin_amdgcn_global_load_lds(gA0 + k0, lA0, 16, 0, 0);
        __builtin_amdgcn_global_load_lds(gA1 + k0, lA1, 16, 0, 0);
        __builtin_amdgcn_global_load_lds(gB0 + k0, lB0, 16, 0, 0);
        __builtin_amdgcn_global_load_lds(gB1 + k0, lB1, 16, 0, 0);
        asm volatile("s_waitcnt vmcnt(0)" ::: "memory");
        __syncthreads();                    // staged data visible block-wide

        short8 a[4], b[4];
#pragma unroll
        for (int mt = 0; mt < 4; ++mt)
            a[mt] = *(const short8*)&As[wm + mt * 16 + fr][fo];
#pragma unroll
        for (int nt = 0; nt < 4; ++nt)
            b[nt] = *(const short8*)&Bs[wn + nt * 16 + fr][fo];
#pragma unroll
        for (int mt = 0; mt < 4; ++mt)
#pragma unroll
            for (int nt = 0; nt < 4; ++nt)
                acc[mt][nt] = __builtin_amdgcn_mfma_f32_16x16x32_bf16(
                    a[mt], b[nt], acc[mt][nt], 0, 0, 0);
    }

    const int col = lane & 15;
    const int rq  = (lane >> 4) * 4;
    for (int nt = 0; nt < 4; ++nt) {
        int gcol = n0 + wn + nt * 16 + col;
        float bv = bias[gcol];
        for (int mt = 0; mt < 4; ++mt) {
            for (int r = 0; r < 4; ++r) {
                int grow = m0 + wm + mt * 16 + rq + r;
                C[(size_t)grow * 4096 + gcol] = f32_to_bf16(acc[mt][nt][r] + bv);
            }
        }
    }
}

// ---------- phase 2: persistent recurrence, 64 blocks x 512 threads ----------
// EXACT round-7 core (1519 us, proven): fresh sentinel-filled slot per step,
// data is its own flag, drain-to-zero poll (no load-dest reuse while in flight
// — r5's counted-vmcnt pipelining faulted), one barrier/step via parity-
// double-buffered partial (pad 16->20), register-direct publish (shfl pack).
// r8's flag-indirection REGRESSED (longer serial chain + global lockstep) —
// do not reintroduce.
__global__ __launch_bounds__(512, 1) void lstm_persist(
    const float* __restrict__ Whh,          // [4096][1024] fp32
    const unsigned short* __restrict__ xg,  // bf16 [16384][4096], bias folded
    const float* __restrict__ c0,           // [32][1024] fp32
    unsigned int* __restrict__ hSeq,        // [512][16384] dwords, frag-order h
    float* __restrict__ out) {              // [32][1024] fp32
    __shared__ float partial[2][4][4][32][20];   // 80 KB [par][ks][gate][batch][pad20]

    const int tid  = threadIdx.x;
    const int bid  = blockIdx.x;
    const int j0   = bid * 16;
    const int lane = tid & 63;
    const int wave = tid >> 6;
    const int ks   = wave >> 1;   // K-split 0..3 (256 k each)
    const int nt   = wave & 1;    // batch half (0-15 / 16-31)
    const int col  = lane & 15;
    const int quad = lane >> 4;

    // ---- stage W_hh slice -> A-fragments in VGPRs/AGPRs (once) ----
    short8 af[4][8];
#pragma unroll
    for (int mt = 0; mt < 4; ++mt) {
#pragma unroll
        for (int u = 0; u < 8; ++u) {
            const float* wr = Whh + (size_t)(mt * 1024 + j0 + col) * 1024
                              + (ks * 8 + u) * 32 + quad * 8;
            float4 wa = *(const float4*)wr;
            float4 wb = *(const float4*)(wr + 4);
            short8 v;
            v[0] = (short)f32_to_bf16(wa.x); v[1] = (short)f32_to_bf16(wa.y);
            v[2] = (short)f32_to_bf16(wa.z); v[3] = (short)f32_to_bf16(wa.w);
            v[4] = (short)f32_to_bf16(wb.x); v[5] = (short)f32_to_bf16(wb.y);
            v[6] = (short)f32_to_bf16(wb.z); v[7] = (short)f32_to_bf16(wb.w);
            af[mt][u] = v;
        }
        asm volatile("" ::: "memory");  // cap transient staging register pressure
    }

    const int eb = tid >> 4;     // epilogue batch 0..31
    const int ej = tid & 15;     // epilogue unit  0..15
    float cst = c0[eb * 1024 + j0 + ej];

    const int bofs = nt * 16 + col;    // wave's batch index for B-frag / partial
    const int poff = ((bid * 2 + (ej >> 3)) * 32 + eb) * 4 + ((ej & 7) >> 1);

    __syncthreads();

    for (int t = 0; t < 512; ++t) {
        const unsigned int* hR = hSeq + ((size_t)t << 14);

        // prefetch xg gate inputs (independent of h, consumed in epilogue)
        const unsigned short* px = xg + (size_t)(eb * 512 + t) * 4096 + j0 + ej;
        unsigned short x0 = px[0];
        unsigned short x1 = px[1024];
        unsigned short x2 = px[2048];
        unsigned short x3 = px[3072];

        // poll-load B-fragments: sentinel 0xFFFFFFFF means "not yet written".
        uint4 bv[8];
        for (;;) {
#pragma unroll
            for (int u = 0; u < 8; ++u) {
                int kc = ks * 8 + u;
                const unsigned int* p = hR + ((kc * 4 + quad) * 32 + bofs) * 4;
                asm volatile("global_load_dwordx4 %0, %1, off sc1"
                             : "=v"(bv[u]) : "v"(p) : "memory");
            }
            asm volatile("s_waitcnt vmcnt(0)" ::: "memory");
            __builtin_amdgcn_sched_barrier(0);   // rule #18
            bool ok = true;
#pragma unroll
            for (int u = 0; u < 8; ++u)
                ok = ok && (bv[u].x != 0xFFFFFFFFu) && (bv[u].y != 0xFFFFFFFFu) &&
                           (bv[u].z != 0xFFFFFFFFu) && (bv[u].w != 0xFFFFFFFFu);
            if (__all(ok)) break;
            __builtin_amdgcn_s_sleep(1);
        }

        f32x4 acc[4] = {};
#pragma unroll
        for (int u = 0; u < 8; ++u) {
            union { uint4 u4; short8 s8; } cv;
            cv.u4 = bv[u];
#pragma unroll
            for (int mt = 0; mt < 4; ++mt)
                acc[mt] = __builtin_amdgcn_mfma_f32_16x16x32_bf16(af[mt][u], cv.s8,
                                                                  acc[mt], 0, 0, 0);
        }
        const int p = t & 1;
#pragma unroll
        for (int mt = 0; mt < 4; ++mt)
            *(f32x4*)&partial[p][ks][mt][bofs][quad * 4] = acc[mt];
        __syncthreads();                          // the ONE barrier per step

        float z[4];
#pragma unroll
        for (int q = 0; q < 4; ++q)
            z[q] = partial[p][0][q][eb][ej] + partial[p][1][q][eb][ej] +
                   partial[p][2][q][eb][ej] + partial[p][3][q][eb][ej];
        z[0] += bf16_to_f32(x0);
        z[1] += bf16_to_f32(x1);
        z[2] += bf16_to_f32(x2);
        z[3] += bf16_to_f32(x3);
        float ig = sigm_fast(z[0]);
        float fg = sigm_fast(z[1]);
        float gg = tanh_fast(z[2]);
        float og = sigm_fast(z[3]);
        cst = fg * cst + ig * gg;
        float hn = og * tanh_fast(cst);
        if (t == 511) {                           // uniform: final output, no publish
            out[eb * 1024 + j0 + ej] = hn;
            break;
        }

        // publish straight from registers: pair-pack via shfl, even-ej lanes
        // store one dword; vmcnt(0) INSIDE the asm (store-reg lifetime safety).
        float hp = __shfl_xor(hn, 1);
        unsigned lo16 = f32_to_bf16(hn), hi16 = f32_to_bf16(hp);
        unsigned pack = lo16 | (hi16 << 16);
        unsigned int* pw = hSeq + ((size_t)(t + 1) << 14) + poff;
        if ((ej & 1) == 0) {
            asm volatile("global_store_dword %0, %1, off sc1\n\ts_waitcnt vmcnt(0)"
                         :: "v"(pw), "v"(pack) : "memory");
        }
    }
}

// ---------- launch ----------
extern "C" void kernel_launch(void* const* d_in, const int* in_sizes, int n_in,
                              void* d_out, int out_size, void* d_ws, size_t ws_size,
                              hipStream_t stream) {
    const float* x    = (const float*)d_in[0];  // [32][512][1024]
    const float* h0   = (const float*)d_in[1];  // [32][1024]
    const float* c0   = (const float*)d_in[2];  // [32][1024]
    const float* Wih  = (const float*)d_in[3];  // [4096][1024]
    const float* Whh  = (const float*)d_in[4];  // [4096][1024]
    const float* b_ih = (const float*)d_in[5];  // [4096]
    const float* b_hh = (const float*)d_in[6];  // [4096]
    float* out = (float*)d_out;
    char* ws = (char*)d_ws;

    // workspace layout (within the proven 176,439,296 B):
    //   xg    @ 0          134217728 B (bf16, live through persistent phase)
    //   xA    @ 134217728   33554432 B (bf16 x; DEAD after gemm -> hSeq overlay:
    //                                   512 slots x 65536 B)
    //   wB    @ 167772160    8388608 B (bf16 W_ih)
    //   bias  @ 176160768      16384 B
    unsigned short* xg   = (unsigned short*)(ws);
    unsigned short* xA   = (unsigned short*)(ws + 134217728);
    unsigned short* wB   = (unsigned short*)(ws + 167772160);
    float*          bias = (float*)(ws + 176160768);
    unsigned int*   hSeq = (unsigned int*)(ws + 134217728);  // overlays xA after gemm

    cvt_bf16_kernel<<<16384, 256, 0, stream>>>(x, xA, 16777216);
    cvt_bf16_kernel<<<4096, 256, 0, stream>>>(Wih, wB, 4194304);
    bias_add_kernel<<<16, 256, 0, stream>>>(b_ih, b_hh, bias);

    dim3 g1(32, 128);   // 128x128 tiles over N=4096, M=16384
    gemm_xproj<<<g1, 256, 0, stream>>>(xA, wB, bias, xg);

    // xA dead from here. Sentinel-fill slots 1..511 (slot 0 gets h0 next).
    fill_kernel<<<32704, 256, 0, stream>>>(hSeq + 16384, 0xFFFFFFFFu, 511 * 16384);
    hG_init_kernel<<<64, 256, 0, stream>>>(h0, hSeq);

    lstm_persist<<<64, 512, 0, stream>>>(Whh, xg, c0, hSeq, out);
}